// Round 13
// baseline (341.574 us; speedup 1.0000x reference)
//
#include <hip/hip_runtime.h>
#include <hip/hip_bf16.h>
#include <hip/hip_fp16.h>
#include <math.h>

// ---------------------------------------------------------------------------
// GAT 2-layer forward.
// R23: overlap the independent pipeline roots.
//  (1) bucket-hist FUSED into the GEMM1 dispatch: blocks 0..255 run the
//      histogram (LDS reused from sA), blocks 256.. run GEMM tiles. The two
//      roles share no state (hist->bcnt; gemm->h1/a_s/a_d); memset precedes.
//  (2) W->fp16 conversion inlined into sB staging of both GEMMs (W is 64KB,
//      L2-resident; same (_Float16) cast -> bitwise-identical h). wcvt kernel
//      and Wt buffers deleted.
//  Launch chain: memset -> fused(gemm1+hist) -> binA -> binB -> agg1 ->
//  gemm2 -> agg2 = 6 kernels + 1 memset (was 7+1).
// Carries R22: agg1 = R15 exact (76us FETCH floor), agg2 grouped remainder,
//  binB 512-thread, binA CHUNK=2048 + local scans.
// ---------------------------------------------------------------------------

#define BINBITS 9                 // nodes per bucket = 512
#define NBUCK 256                 // covers N < 131072
#define CHUNK 2048                // edges per WG in binA
#define SPANCAP 12288             // LDS staging capacity in binB (ints)

typedef _Float16 half8 __attribute__((ext_vector_type(8)));
typedef float f32x4 __attribute__((ext_vector_type(4)));

// ------------------------- CSR build -------------------------

// binA: per-chunk bucket scatter. Computes the global bucket-base scan
// locally (lockstep with its chunk scan); placement = gexc + bfill atomic.
__launch_bounds__(256)
__global__ void binA_kernel(const int* __restrict__ esrc, const int* __restrict__ edst,
                            const int* __restrict__ bcnt, int* __restrict__ bfill,
                            unsigned* __restrict__ binned, int E) {
    __shared__ unsigned stage[CHUNK];
    __shared__ int hcnt[NBUCK], hexc[NBUCK], gb[NBUCK], hfill[NBUCK], gbase[NBUCK];
    const int tid = threadIdx.x;
    const int c0 = blockIdx.x * CHUNK;
    const int n = min(CHUNK, E - c0);

    hcnt[tid] = 0;
    hfill[tid] = 0;
    int myg = bcnt[tid];                        // global bucket count (post-hist)
    gbase[tid] = myg;
    __syncthreads();
    for (int i = tid; i < n; i += 256) atomicAdd(&hcnt[edst[c0 + i] >> BINBITS], 1);
    __syncthreads();
    int myc = hcnt[tid];
    hexc[tid] = myc;
    __syncthreads();
    for (int o = 1; o < NBUCK; o <<= 1) {       // two inclusive scans, lockstep
        int x = (tid >= o) ? hexc[tid - o] : 0;
        int y = (tid >= o) ? gbase[tid - o] : 0;
        __syncthreads();
        hexc[tid] += x;
        gbase[tid] += y;
        __syncthreads();
    }
    hexc[tid] -= myc;                           // exclusive (chunk-local)
    int gexc = gbase[tid] - myg;                // exclusive (global bucket base)
    gb[tid] = myc ? (gexc + atomicAdd(&bfill[tid], myc)) : 0;
    __syncthreads();

    for (int i = tid; i < n; i += 256) {
        int d = edst[c0 + i], s = esrc[c0 + i];
        int b = d >> BINBITS;
        int p = hexc[b] + atomicAdd(&hfill[b], 1);
        stage[p] = ((unsigned)(d & ((1 << BINBITS) - 1)) << 17) | (unsigned)s;
    }
    __syncthreads();

    // copy-out: 4 buckets per wave in parallel, 16-lane sub-groups (R20)
    const int wid = tid >> 6, lane = tid & 63;
    const int sg = lane >> 4, sl = lane & 15;
    for (int bb = wid * 64; bb < wid * 64 + 64; bb += 4) {
        int b = bb + sg;
        int cnt = hcnt[b], sb = hexc[b], g = gb[b];
        for (int l = sl; l < cnt; l += 16) binned[g + l] = stage[sb + l];
    }
}

// binB (R22): 512 threads/block, one bucket (512 nodes) per block.
__launch_bounds__(512)
__global__ void binB_kernel(const unsigned* __restrict__ binned, const int* __restrict__ bcnt,
                            int* __restrict__ rowptr, int* __restrict__ csr, int N) {
    __shared__ int cnt[512];           // degree count, then reused as fill
    __shared__ int sscan[512];
    __shared__ int excl[513];
    __shared__ int stag[SPANCAP];
    __shared__ int sE0, sE1;
    const int tid = threadIdx.x;       // 0..511
    const int b = blockIdx.x;
    const int node0 = b << BINBITS;
    if (node0 >= N) return;
    const int nn = min(512, N - node0);

    // bucket edge range: local scan of bcnt[256]
    if (tid < NBUCK) sscan[tid] = bcnt[tid];
    cnt[tid] = (tid < nn) ? 1 : 0;            // self-loop seed
    __syncthreads();
    for (int o = 1; o < NBUCK; o <<= 1) {
        int x = (tid < NBUCK && tid >= o) ? sscan[tid - o] : 0;
        __syncthreads();
        if (tid < NBUCK) sscan[tid] += x;
        __syncthreads();
    }
    if (tid == b) {                           // b < NBUCK always (N < 131072)
        sE1 = sscan[b];
        sE0 = sscan[b] - bcnt[b];
    }
    __syncthreads();
    const int e0 = sE0, e1 = sE1;

    for (int i = e0 + tid; i < e1; i += 512)
        atomicAdd(&cnt[binned[i] >> 17], 1);
    __syncthreads();

    int v = cnt[tid];
    sscan[tid] = v;
    __syncthreads();
    for (int o = 1; o < 512; o <<= 1) {
        int x = (tid >= o) ? sscan[tid - o] : 0;
        __syncthreads();
        sscan[tid] += x;
        __syncthreads();
    }
    excl[tid] = sscan[tid] - v;
    if (tid == 511) excl[512] = sscan[511];
    __syncthreads();

    const int rbase = e0 + node0;             // == rowptr[node0]
    if (tid < nn) rowptr[node0 + tid] = rbase + excl[tid];
    if (node0 + nn >= N && tid == 0) rowptr[N] = rbase + excl[512];

    cnt[tid] = 0;
    __syncthreads();
    const int span = excl[512];

    if (span <= SPANCAP) {
        for (int i = e0 + tid; i < e1; i += 512) {
            unsigned e = binned[i];
            int dloc = e >> 17, src = e & 0x1FFFF;
            int p = excl[dloc] + atomicAdd(&cnt[dloc], 1);
            stag[p] = src;
        }
        if (tid < nn) {
            int p = excl[tid] + atomicAdd(&cnt[tid], 1);
            stag[p] = node0 + tid;
        }
        __syncthreads();
        for (int i = tid; i < span; i += 512) csr[rbase + i] = stag[i];
    } else {
        for (int i = e0 + tid; i < e1; i += 512) {
            unsigned e = binned[i];
            int dloc = e >> 17, src = e & 0x1FFFF;
            csr[rbase + excl[dloc] + atomicAdd(&cnt[dloc], 1)] = src;
        }
        if (tid < nn)
            csr[rbase + excl[tid] + atomicAdd(&cnt[tid], 1)] = node0 + tid;
    }
}

// ------ MFMA GEMM (fp16 in, fp32 acc) + attn epilogue [+ fused hist] ------
// Blocks [0, histBlocks): bucket histogram role (independent root; LDS
// reused from sA). Blocks [histBlocks, ..): 256 threads = 4 waves; block
// tile BM=128 rows x FOUT cols, whole K in LDS. W -> fp16 conversion
// inlined into sB staging (R23; W is L2-resident).
// Layouts (verified): A[m=lane&15][k=quad*8+j]  B[k=quad*8+j][n=lane&15]
//   C/D: col=lane&15, row=quad*4+reg

template <int FIN, int FOUT, typename XT>
__launch_bounds__(256)
__global__ void gemm_attn_mfma(const XT* __restrict__ X, const float* __restrict__ W,
                               const float* __restrict__ atts, const float* __restrict__ attd,
                               __half* __restrict__ Hh, float* __restrict__ a_s,
                               float* __restrict__ a_d, int N,
                               const int* __restrict__ edst, int* __restrict__ bcnt, int E,
                               int histBlocks) {
    constexpr int BM = 128;
    constexpr int C = FOUT / 2;
    constexpr int NT = FOUT / 16;     // n-tiles per wave (8 / 4)
    constexpr int KS = FIN / 32;      // k-steps (4 / 2)
    constexpr int HT = C / 16;        // n-tiles per head
    __shared__ _Float16 sA[BM * FIN];
    __shared__ _Float16 sB[FOUT * FIN];

    const int tid = threadIdx.x;

    // ---- fused hist role (layer 1 only; blocks 0..histBlocks-1) ----
    if (blockIdx.x < histBlocks) {
        int* h = (int*)sA;            // 256 ints, reuse LDS
        h[tid] = 0;
        __syncthreads();
        for (int i = blockIdx.x * 256 + tid; i < E; i += histBlocks * 256)
            atomicAdd(&h[edst[i] >> BINBITS], 1);
        __syncthreads();
        if (h[tid]) atomicAdd(&bcnt[tid], h[tid]);
        return;
    }

    const int wv = tid >> 6, ln = tid & 63;
    const int lm = ln & 15, quad = ln >> 4;
    const int row0 = (blockIdx.x - histBlocks) * BM;

    // ---- stage A (rows, k contiguous) ----
    if (sizeof(XT) == 4) {
        for (int idx = tid; idx < BM * FIN / 4; idx += 256) {
            int r = idx / (FIN / 4), c4 = idx % (FIN / 4);
            int gr = row0 + r;
            float4 v = make_float4(0.f, 0.f, 0.f, 0.f);
            if (gr < N) v = *(const float4*)&((const float*)X)[(size_t)gr * FIN + c4 * 4];
            _Float16 h4[4] = {(_Float16)v.x, (_Float16)v.y, (_Float16)v.z, (_Float16)v.w};
            *(float2*)&sA[r * FIN + c4 * 4] = *(float2*)h4;
        }
    } else {
        for (int idx = tid; idx < BM * FIN / 8; idx += 256) {
            int r = idx / (FIN / 8), c8 = idx % (FIN / 8);
            int gr = row0 + r;
            int4 v = make_int4(0, 0, 0, 0);
            if (gr < N) v = *(const int4*)&((const __half*)X)[(size_t)gr * FIN + c8 * 8];
            *(int4*)&sA[r * FIN + c8 * 8] = v;
        }
    }
    // ---- stage B: on-the-fly W[k][n] -> sB[n][k] fp16 (R23) ----
    for (int idx = tid; idx < FOUT * FIN / 8; idx += 256) {
        int n = idx / (FIN / 8);
        int k8 = (idx % (FIN / 8)) * 8;
        _Float16 t8[8];
#pragma unroll
        for (int j = 0; j < 8; ++j) t8[j] = (_Float16)W[(size_t)(k8 + j) * FOUT + n];
        *(int4*)&sB[n * FIN + k8] = *(const int4*)t8;
    }
    __syncthreads();

    // ---- MFMA K-loop ----
    f32x4 acc[2][NT];
#pragma unroll
    for (int mt = 0; mt < 2; ++mt)
#pragma unroll
        for (int nt = 0; nt < NT; ++nt) acc[mt][nt] = f32x4{0.f, 0.f, 0.f, 0.f};

    const int r0 = wv * 32 + lm;
#pragma unroll
    for (int ks = 0; ks < KS; ++ks) {
        int k0 = ks * 32 + quad * 8;
        half8 a0 = *(const half8*)&sA[r0 * FIN + k0];
        half8 a1 = *(const half8*)&sA[(r0 + 16) * FIN + k0];
#pragma unroll
        for (int nt = 0; nt < NT; ++nt) {
            half8 b = *(const half8*)&sB[(nt * 16 + lm) * FIN + k0];
            acc[0][nt] = __builtin_amdgcn_mfma_f32_16x16x32_f16(a0, b, acc[0][nt], 0, 0, 0);
            acc[1][nt] = __builtin_amdgcn_mfma_f32_16x16x32_f16(a1, b, acc[1][nt], 0, 0, 0);
        }
    }

    // ---- attn scalars from fp32 acc ----
    float psum[2][4][2], pdum[2][4][2];  // [mt][reg][head]
#pragma unroll
    for (int mt = 0; mt < 2; ++mt)
#pragma unroll
        for (int r = 0; r < 4; ++r) {
            psum[mt][r][0] = psum[mt][r][1] = 0.f;
            pdum[mt][r][0] = pdum[mt][r][1] = 0.f;
        }
#pragma unroll
    for (int nt = 0; nt < NT; ++nt) {
        float av = atts[nt * 16 + lm];
        float dv = attd[nt * 16 + lm];
        int hh = nt / HT;
#pragma unroll
        for (int mt = 0; mt < 2; ++mt)
#pragma unroll
            for (int r = 0; r < 4; ++r) {
                psum[mt][r][hh] = fmaf(acc[mt][nt][r], av, psum[mt][r][hh]);
                pdum[mt][r][hh] = fmaf(acc[mt][nt][r], dv, pdum[mt][r][hh]);
            }
    }
#pragma unroll
    for (int o = 1; o < 16; o <<= 1) {
#pragma unroll
        for (int mt = 0; mt < 2; ++mt)
#pragma unroll
            for (int r = 0; r < 4; ++r) {
                psum[mt][r][0] += __shfl_xor(psum[mt][r][0], o);
                psum[mt][r][1] += __shfl_xor(psum[mt][r][1], o);
                pdum[mt][r][0] += __shfl_xor(pdum[mt][r][0], o);
                pdum[mt][r][1] += __shfl_xor(pdum[mt][r][1], o);
            }
    }
    if (lm == 0) {
#pragma unroll
        for (int mt = 0; mt < 2; ++mt)
#pragma unroll
            for (int r = 0; r < 4; ++r) {
                int gr = row0 + wv * 32 + mt * 16 + quad * 4 + r;
                if (gr < N) {
                    *(float2*)&a_s[gr * 2] = make_float2(psum[mt][r][0], psum[mt][r][1]);
                    *(float2*)&a_d[gr * 2] = make_float2(pdum[mt][r][0], pdum[mt][r][1]);
                }
            }
    }

    // ---- h -> fp16 via LDS transpose (reuse sA), coalesced store ----
    __syncthreads();
    _Float16* sH = sA;  // BM*FOUT <= BM*FIN
#pragma unroll
    for (int mt = 0; mt < 2; ++mt)
#pragma unroll
        for (int nt = 0; nt < NT; ++nt)
#pragma unroll
            for (int r = 0; r < 4; ++r)
                sH[(wv * 32 + mt * 16 + quad * 4 + r) * FOUT + nt * 16 + lm] =
                    (_Float16)acc[mt][nt][r];
    __syncthreads();
    for (int idx = tid; idx < BM * FOUT / 8; idx += 256) {
        int r = idx / (FOUT / 8), c8 = idx % (FOUT / 8);
        int gr = row0 + r;
        if (gr < N)
            *(int4*)&Hh[(size_t)gr * FOUT + c8 * 8] = *(const int4*)&sH[r * FOUT + c8 * 8];
    }
}

// --------------------- fused weighted gather aggregation ------------------
// One wave per node, no LDS. Per 64-edge chunk: lane j loads csr[j] -> src.
// Gather ADDRESSES are broadcast to lanes via __shfl of src*RI immediately
// (only dependence: the csr load), so the 4-deep h-row loads issue while the
// weight chain (a_s[src] random load -> exp) is still in flight. Weights
// reach the FMA via 2 __shfl + select. LPE lanes per edge (C=64: LPE=16,
// NG=4; C=32: LPE=8, NG=8); lane loads int4 = 8 channels; fma_mix.
// Remainder: C=64 keeps R15's 1-deep serial remainder (32-VGPR floor);
// C=32 uses the grouped remainder (deg<=24 rows: 3 serial L3 round-trips
// -> 1). Pad slots: e=0, src=0 -> fma no-op. Normalization deferred:
// av *= 0.5/denom[head] before the head fold.

__device__ __forceinline__ float lrelu02(float x) { return x > 0.f ? x : 0.2f * x; }

template <int C, bool ELU, typename OT>
__launch_bounds__(256)
__global__ void aggregate_kernel(const __half* __restrict__ Hh,
                                 const float* __restrict__ a_s, const float* __restrict__ a_d,
                                 const int* __restrict__ rowptr, const int* __restrict__ csr,
                                 const float* __restrict__ bias, OT* __restrict__ out, int N) {
    constexpr int LPE = (C == 64) ? 16 : 8;   // lanes per edge
    constexpr int NG = 64 / LPE;              // edges per batch
    constexpr int RI = C / 4;                 // int4 per h row (2C halves)
    const int wid = threadIdx.x >> 6;
    const int lane = threadIdx.x & 63;
    const int sub = lane & (LPE - 1);
    const int qid = lane / LPE;               // edge-within-batch
    const int myH = (sub >= LPE / 2);         // this lane's head
    int n = blockIdx.x * 4 + wid;
    if (n >= N) return;
    int start = rowptr[n], end = rowptr[n + 1];
    const int4* HI = (const int4*)Hh;
    float2 adn = ((const float2*)a_d)[n];

    float av[8];
#pragma unroll
    for (int j = 0; j < 8; ++j) av[j] = 0.f;
    float d0 = 0.f, d1 = 0.f;

    for (int cs = start; cs < end; cs += 64) {
        int j = cs + lane;
        int s = 0;
        if (j < end) s = csr[j];              // masked lanes: src 0
        int sri = (int)((unsigned)s * RI);
        int cnt = min(64, end - cs);
        int nbatch = (cnt + NG - 1) / NG;     // wave-uniform

        // weight chain (independent of gather addressing; overlaps h-loads)
        float2 asv = ((const float2*)a_s)[s]; // s=0 for masked lanes: safe
        float e0 = 0.f, e1 = 0.f;
        if (j < end) {
            e0 = __expf(lrelu02(asv.x + adn.x));
            e1 = __expf(lrelu02(asv.y + adn.y));
        }
        d0 += e0;
        d1 += e1;

        int b = 0;
        for (; b + 4 <= nbatch; b += 4) {     // 4-deep exact main
            int adr[4];
#pragma unroll
            for (int u = 0; u < 4; ++u)
                adr[u] = __shfl(sri, (b + u) * NG + qid);   // addr: csr-only dep
            int4 hv[4];
#pragma unroll
            for (int u = 0; u < 4; ++u)
                hv[u] = HI[(unsigned)adr[u] + (unsigned)sub];
#pragma unroll
            for (int u = 0; u < 4; ++u) {
                int slot = (b + u) * NG + qid;
                float w0 = __shfl(e0, slot);
                float w1 = __shfl(e1, slot);
                float ww = myH ? w1 : w0;
                const _Float16* hh = (const _Float16*)&hv[u];
#pragma unroll
                for (int k = 0; k < 8; ++k)
                    av[k] = fmaf(ww, (float)hh[k], av[k]);  // v_fma_mix_f32
            }
        }
        if constexpr (C == 32) {
            int rem = nbatch - b;             // 0..3, wave-uniform
            if (rem > 0) {                    // grouped remainder (agg2 only)
                int4 hvr[3];
#pragma unroll
                for (int u = 0; u < 3; ++u) {
                    if (u < rem) {            // wave-uniform guard
                        int adr = __shfl(sri, (b + u) * NG + qid);
                        hvr[u] = HI[(unsigned)adr + (unsigned)sub];
                    }
                }
#pragma unroll
                for (int u = 0; u < 3; ++u) {
                    if (u < rem) {            // wave-uniform guard
                        int slot = (b + u) * NG + qid;
                        float w0 = __shfl(e0, slot);
                        float w1 = __shfl(e1, slot);
                        float ww = myH ? w1 : w0;
                        const _Float16* hh = (const _Float16*)&hvr[u];
#pragma unroll
                        for (int k = 0; k < 8; ++k)
                            av[k] = fmaf(ww, (float)hh[k], av[k]);
                    }
                }
            }
        } else {
            for (; b < nbatch; ++b) {         // 1-deep serial remainder (agg1)
                int slot = b * NG + qid;
                int adr = __shfl(sri, slot);
                int4 hv = HI[(unsigned)adr + (unsigned)sub];
                float w0 = __shfl(e0, slot);
                float w1 = __shfl(e1, slot);
                float ww = myH ? w1 : w0;
                const _Float16* hh = (const _Float16*)&hv;
#pragma unroll
                for (int k = 0; k < 8; ++k)
                    av[k] = fmaf(ww, (float)hh[k], av[k]);  // v_fma_mix_f32
            }
        }
    }

    // merge edge subsets (groups of LPE lanes)
#pragma unroll
    for (int o = LPE; o < 64; o <<= 1)
#pragma unroll
        for (int j = 0; j < 8; ++j) av[j] += __shfl_xor(av[j], o);
    // denominator: every lane holds a partial (one edge-slot per chunk)
#pragma unroll
    for (int o = 32; o > 0; o >>= 1) {
        d0 += __shfl_xor(d0, o);
        d1 += __shfl_xor(d1, o);
    }
    float sc = myH ? (0.5f / d1) : (0.5f / d0);  // 0.5 = head mean
#pragma unroll
    for (int j = 0; j < 8; ++j) av[j] *= sc;
    // head fold: ch c (head0) + ch c+C (head1)
#pragma unroll
    for (int j = 0; j < 8; ++j) av[j] += __shfl_xor(av[j], LPE / 2);

    if (lane < LPE / 2) {
        float4 b0 = *(const float4*)(bias + sub * 8);
        float4 b1 = *(const float4*)(bias + sub * 8 + 4);
        float o0[8];
        o0[0] = av[0] + b0.x; o0[1] = av[1] + b0.y;
        o0[2] = av[2] + b0.z; o0[3] = av[3] + b0.w;
        o0[4] = av[4] + b1.x; o0[5] = av[5] + b1.y;
        o0[6] = av[6] + b1.z; o0[7] = av[7] + b1.w;
        if (ELU) {
#pragma unroll
            for (int j = 0; j < 8; ++j) o0[j] = o0[j] > 0.f ? o0[j] : expm1f(o0[j]);
        }
        if (sizeof(OT) == 2) {
            union { int4 v; __half2 h2[4]; } u;
#pragma unroll
            for (int p = 0; p < 4; ++p) u.h2[p] = __floats2half2_rn(o0[2 * p], o0[2 * p + 1]);
            *(int4*)((__half*)out + (size_t)n * C + sub * 8) = u.v;
        } else {
            *(float4*)((float*)out + (size_t)n * C + sub * 8) =
                make_float4(o0[0], o0[1], o0[2], o0[3]);
            *(float4*)((float*)out + (size_t)n * C + sub * 8 + 4) =
                make_float4(o0[4], o0[5], o0[6], o0[7]);
        }
    }
}

// ------------------------- launch -------------------------

extern "C" void kernel_launch(void* const* d_in, const int* in_sizes, int n_in,
                              void* d_out, int out_size, void* d_ws, size_t ws_size,
                              hipStream_t stream) {
    const float* x    = (const float*)d_in[0];
    const int*   eidx = (const int*)d_in[1];
    const float* W1   = (const float*)d_in[2];
    const float* as1w = (const float*)d_in[3];
    const float* ad1w = (const float*)d_in[4];
    const float* b1   = (const float*)d_in[5];
    const float* W2   = (const float*)d_in[6];
    const float* as2w = (const float*)d_in[7];
    const float* ad2w = (const float*)d_in[8];
    const float* b2   = (const float*)d_in[9];
    float* out = (float*)d_out;

    const int N = in_sizes[0] / 128;  // Fin = 128
    const int E = in_sizes[1] / 2;
    const int NBK = (N + (1 << BINBITS) - 1) >> BINBITS;

    char* base = (char*)d_ws;
    size_t off = 0;
    auto alloc = [&](size_t bytes) {
        size_t cur = off;
        off += (bytes + 255) & ~(size_t)255;
        return (void*)(base + cur);
    };

    int* rowptr   = (int*)alloc((size_t)(N + 1) * 4);
    int* csr      = (int*)alloc((size_t)(E + N) * 4);
    int* bcbf     = (int*)alloc((size_t)512 * 4);        // [0:256)=bcnt, [256:512)=bfill
    unsigned* binned = (unsigned*)alloc((size_t)E * 4);
    __half* h1    = (__half*)alloc((size_t)N * 128 * 2);  // fp16, reused as h2
    __half* x2h   = (__half*)alloc((size_t)N * 64 * 2);   // fp16 layer-2 input
    float* a_s    = (float*)alloc((size_t)N * 2 * 4);
    float* a_d    = (float*)alloc((size_t)N * 2 * 4);

    int* bcnt  = bcbf;
    int* bfill = bcbf + 256;
    const int* esrc = eidx;
    const int* edst = eidx + E;

    // --- init ---
    hipMemsetAsync(bcbf, 0, 512 * 4, stream);

    // --- Layer 1 GEMM fused with bucket-hist (independent roots) ---
    const int gemm1Blocks = (N + 127) / 128;
    gemm_attn_mfma<128, 128, float>
        <<<256 + gemm1Blocks, 256, 0, stream>>>(x, W1, as1w, ad1w, h1, a_s, a_d, N,
                                                edst, bcnt, E, 256);

    // --- CSR build (shared by both layers) ---
    binA_kernel<<<(E + CHUNK - 1) / CHUNK, 256, 0, stream>>>(esrc, edst, bcnt, bfill, binned, E);
    binB_kernel<<<NBK, 512, 0, stream>>>(binned, bcnt, rowptr, csr, N);

    // --- Layer 1 aggregate ---
    aggregate_kernel<64, true, __half>
        <<<(N + 3) / 4, 256, 0, stream>>>(h1, a_s, a_d, rowptr, csr, b1, x2h, N);

    // --- Layer 2 (Fin=64 -> H=2, C=32) ---
    gemm_attn_mfma<64, 64, __half>
        <<<(N + 127) / 128, 256, 0, stream>>>(x2h, W2, as2w, ad2w, h1, a_s, a_d, N,
                                              nullptr, nullptr, 0, 0);
    aggregate_kernel<32, false, float>
        <<<(N + 3) / 4, 256, 0, stream>>>(h1, a_s, a_d, rowptr, csr, b2, out, N);
}

// Round 14
// 327.793 us; speedup vs baseline: 1.0420x; 1.0420x over previous
//
#include <hip/hip_runtime.h>
#include <hip/hip_bf16.h>
#include <hip/hip_fp16.h>
#include <math.h>

// ---------------------------------------------------------------------------
// GAT 2-layer forward.
// R24: R23's W-inline reverted (uncoalesced stride-FOUT W reads in every GEMM
//      block caused the +7.7us regression). Kept: hist role fused into the
//      GEMM1 dispatch (the one dependency-legal overlap: hist->bcnt feeds
//      binA; GEMM1 feeds agg1). wcvt restored as standalone coalesced kernel;
//      GEMM reads Wt fp16 contiguously (R22 exact).
//      Chain: memset -> wcvt -> gemm1||hist -> binA -> binB -> agg1 ->
//      gemm2 -> agg2.
// Carries R22: agg1 = R15 exact (76us FETCH floor: 210.7MB @ 2.77TB/s,
//  invariant across 7 structures), agg2 grouped remainder, binB 512-thread,
//  binA CHUNK=2048 + local scans.
// ---------------------------------------------------------------------------

#define BINBITS 9                 // nodes per bucket = 512
#define NBUCK 256                 // covers N < 131072
#define CHUNK 2048                // edges per WG in binA
#define SPANCAP 12288             // LDS staging capacity in binB (ints)

typedef _Float16 half8 __attribute__((ext_vector_type(8)));
typedef float f32x4 __attribute__((ext_vector_type(4)));

// ------------------- W -> fp16 transposed (both layers) -------------------

__global__ void wcvt_kernel(const float* __restrict__ W1, _Float16* __restrict__ Wt1,
                            const float* __restrict__ W2, _Float16* __restrict__ Wt2) {
    int i = blockIdx.x * 256 + threadIdx.x;
    if (i < 128 * 128) {
        int n = i >> 7, k = i & 127;
        Wt1[i] = (_Float16)W1[k * 128 + n];
    }
    int j = i - 128 * 128;
    if (j >= 0 && j < 64 * 64) {
        int n = j >> 6, k = j & 63;
        Wt2[j] = (_Float16)W2[k * 64 + n];
    }
}

// ------------------------- CSR build -------------------------

// binA: per-chunk bucket scatter. Computes the global bucket-base scan
// locally (lockstep with its chunk scan); placement = gexc + bfill atomic.
__launch_bounds__(256)
__global__ void binA_kernel(const int* __restrict__ esrc, const int* __restrict__ edst,
                            const int* __restrict__ bcnt, int* __restrict__ bfill,
                            unsigned* __restrict__ binned, int E) {
    __shared__ unsigned stage[CHUNK];
    __shared__ int hcnt[NBUCK], hexc[NBUCK], gb[NBUCK], hfill[NBUCK], gbase[NBUCK];
    const int tid = threadIdx.x;
    const int c0 = blockIdx.x * CHUNK;
    const int n = min(CHUNK, E - c0);

    hcnt[tid] = 0;
    hfill[tid] = 0;
    int myg = bcnt[tid];                        // global bucket count (post-hist)
    gbase[tid] = myg;
    __syncthreads();
    for (int i = tid; i < n; i += 256) atomicAdd(&hcnt[edst[c0 + i] >> BINBITS], 1);
    __syncthreads();
    int myc = hcnt[tid];
    hexc[tid] = myc;
    __syncthreads();
    for (int o = 1; o < NBUCK; o <<= 1) {       // two inclusive scans, lockstep
        int x = (tid >= o) ? hexc[tid - o] : 0;
        int y = (tid >= o) ? gbase[tid - o] : 0;
        __syncthreads();
        hexc[tid] += x;
        gbase[tid] += y;
        __syncthreads();
    }
    hexc[tid] -= myc;                           // exclusive (chunk-local)
    int gexc = gbase[tid] - myg;                // exclusive (global bucket base)
    gb[tid] = myc ? (gexc + atomicAdd(&bfill[tid], myc)) : 0;
    __syncthreads();

    for (int i = tid; i < n; i += 256) {
        int d = edst[c0 + i], s = esrc[c0 + i];
        int b = d >> BINBITS;
        int p = hexc[b] + atomicAdd(&hfill[b], 1);
        stage[p] = ((unsigned)(d & ((1 << BINBITS) - 1)) << 17) | (unsigned)s;
    }
    __syncthreads();

    // copy-out: 4 buckets per wave in parallel, 16-lane sub-groups (R20)
    const int wid = tid >> 6, lane = tid & 63;
    const int sg = lane >> 4, sl = lane & 15;
    for (int bb = wid * 64; bb < wid * 64 + 64; bb += 4) {
        int b = bb + sg;
        int cnt = hcnt[b], sb = hexc[b], g = gb[b];
        for (int l = sl; l < cnt; l += 16) binned[g + l] = stage[sb + l];
    }
}

// binB (R22): 512 threads/block, one bucket (512 nodes) per block.
__launch_bounds__(512)
__global__ void binB_kernel(const unsigned* __restrict__ binned, const int* __restrict__ bcnt,
                            int* __restrict__ rowptr, int* __restrict__ csr, int N) {
    __shared__ int cnt[512];           // degree count, then reused as fill
    __shared__ int sscan[512];
    __shared__ int excl[513];
    __shared__ int stag[SPANCAP];
    __shared__ int sE0, sE1;
    const int tid = threadIdx.x;       // 0..511
    const int b = blockIdx.x;
    const int node0 = b << BINBITS;
    if (node0 >= N) return;
    const int nn = min(512, N - node0);

    // bucket edge range: local scan of bcnt[256]
    if (tid < NBUCK) sscan[tid] = bcnt[tid];
    cnt[tid] = (tid < nn) ? 1 : 0;            // self-loop seed
    __syncthreads();
    for (int o = 1; o < NBUCK; o <<= 1) {
        int x = (tid < NBUCK && tid >= o) ? sscan[tid - o] : 0;
        __syncthreads();
        if (tid < NBUCK) sscan[tid] += x;
        __syncthreads();
    }
    if (tid == b) {                           // b < NBUCK always (N < 131072)
        sE1 = sscan[b];
        sE0 = sscan[b] - bcnt[b];
    }
    __syncthreads();
    const int e0 = sE0, e1 = sE1;

    for (int i = e0 + tid; i < e1; i += 512)
        atomicAdd(&cnt[binned[i] >> 17], 1);
    __syncthreads();

    int v = cnt[tid];
    sscan[tid] = v;
    __syncthreads();
    for (int o = 1; o < 512; o <<= 1) {
        int x = (tid >= o) ? sscan[tid - o] : 0;
        __syncthreads();
        sscan[tid] += x;
        __syncthreads();
    }
    excl[tid] = sscan[tid] - v;
    if (tid == 511) excl[512] = sscan[511];
    __syncthreads();

    const int rbase = e0 + node0;             // == rowptr[node0]
    if (tid < nn) rowptr[node0 + tid] = rbase + excl[tid];
    if (node0 + nn >= N && tid == 0) rowptr[N] = rbase + excl[512];

    cnt[tid] = 0;
    __syncthreads();
    const int span = excl[512];

    if (span <= SPANCAP) {
        for (int i = e0 + tid; i < e1; i += 512) {
            unsigned e = binned[i];
            int dloc = e >> 17, src = e & 0x1FFFF;
            int p = excl[dloc] + atomicAdd(&cnt[dloc], 1);
            stag[p] = src;
        }
        if (tid < nn) {
            int p = excl[tid] + atomicAdd(&cnt[tid], 1);
            stag[p] = node0 + tid;
        }
        __syncthreads();
        for (int i = tid; i < span; i += 512) csr[rbase + i] = stag[i];
    } else {
        for (int i = e0 + tid; i < e1; i += 512) {
            unsigned e = binned[i];
            int dloc = e >> 17, src = e & 0x1FFFF;
            csr[rbase + excl[dloc] + atomicAdd(&cnt[dloc], 1)] = src;
        }
        if (tid < nn)
            csr[rbase + excl[tid] + atomicAdd(&cnt[tid], 1)] = node0 + tid;
    }
}

// ------ MFMA GEMM (fp16 in, fp32 acc) + attn epilogue [+ fused hist] ------
// Blocks [0, histBlocks): bucket histogram role (independent root; LDS
// reused from sA). Blocks [histBlocks, ..): 256 threads = 4 waves; block
// tile BM=128 rows x FOUT cols, whole K in LDS. B read from Wt (fp16,
// contiguous -- R24: coalesced wcvt restored).
// Layouts (verified): A[m=lane&15][k=quad*8+j]  B[k=quad*8+j][n=lane&15]
//   C/D: col=lane&15, row=quad*4+reg

template <int FIN, int FOUT, typename XT>
__launch_bounds__(256)
__global__ void gemm_attn_mfma(const XT* __restrict__ X, const _Float16* __restrict__ Wt,
                               const float* __restrict__ atts, const float* __restrict__ attd,
                               __half* __restrict__ Hh, float* __restrict__ a_s,
                               float* __restrict__ a_d, int N,
                               const int* __restrict__ edst, int* __restrict__ bcnt, int E,
                               int histBlocks) {
    constexpr int BM = 128;
    constexpr int C = FOUT / 2;
    constexpr int NT = FOUT / 16;     // n-tiles per wave (8 / 4)
    constexpr int KS = FIN / 32;      // k-steps (4 / 2)
    constexpr int HT = C / 16;        // n-tiles per head
    __shared__ _Float16 sA[BM * FIN];
    __shared__ _Float16 sB[FOUT * FIN];

    const int tid = threadIdx.x;

    // ---- fused hist role (layer 1 only; blocks 0..histBlocks-1) ----
    if (blockIdx.x < histBlocks) {
        int* h = (int*)sA;            // 256 ints, reuse LDS
        h[tid] = 0;
        __syncthreads();
        for (int i = blockIdx.x * 256 + tid; i < E; i += histBlocks * 256)
            atomicAdd(&h[edst[i] >> BINBITS], 1);
        __syncthreads();
        if (h[tid]) atomicAdd(&bcnt[tid], h[tid]);
        return;
    }

    const int wv = tid >> 6, ln = tid & 63;
    const int lm = ln & 15, quad = ln >> 4;
    const int row0 = (blockIdx.x - histBlocks) * BM;

    // ---- stage A (rows, k contiguous) ----
    if (sizeof(XT) == 4) {
        for (int idx = tid; idx < BM * FIN / 4; idx += 256) {
            int r = idx / (FIN / 4), c4 = idx % (FIN / 4);
            int gr = row0 + r;
            float4 v = make_float4(0.f, 0.f, 0.f, 0.f);
            if (gr < N) v = *(const float4*)&((const float*)X)[(size_t)gr * FIN + c4 * 4];
            _Float16 h4[4] = {(_Float16)v.x, (_Float16)v.y, (_Float16)v.z, (_Float16)v.w};
            *(float2*)&sA[r * FIN + c4 * 4] = *(float2*)h4;
        }
    } else {
        for (int idx = tid; idx < BM * FIN / 8; idx += 256) {
            int r = idx / (FIN / 8), c8 = idx % (FIN / 8);
            int gr = row0 + r;
            int4 v = make_int4(0, 0, 0, 0);
            if (gr < N) v = *(const int4*)&((const __half*)X)[(size_t)gr * FIN + c8 * 8];
            *(int4*)&sA[r * FIN + c8 * 8] = v;
        }
    }
    // ---- stage B (Wt contiguous copy) ----
    for (int idx = tid; idx < FOUT * FIN / 8; idx += 256)
        *(int4*)&sB[idx * 8] = *(const int4*)&Wt[idx * 8];
    __syncthreads();

    // ---- MFMA K-loop ----
    f32x4 acc[2][NT];
#pragma unroll
    for (int mt = 0; mt < 2; ++mt)
#pragma unroll
        for (int nt = 0; nt < NT; ++nt) acc[mt][nt] = f32x4{0.f, 0.f, 0.f, 0.f};

    const int r0 = wv * 32 + lm;
#pragma unroll
    for (int ks = 0; ks < KS; ++ks) {
        int k0 = ks * 32 + quad * 8;
        half8 a0 = *(const half8*)&sA[r0 * FIN + k0];
        half8 a1 = *(const half8*)&sA[(r0 + 16) * FIN + k0];
#pragma unroll
        for (int nt = 0; nt < NT; ++nt) {
            half8 b = *(const half8*)&sB[(nt * 16 + lm) * FIN + k0];
            acc[0][nt] = __builtin_amdgcn_mfma_f32_16x16x32_f16(a0, b, acc[0][nt], 0, 0, 0);
            acc[1][nt] = __builtin_amdgcn_mfma_f32_16x16x32_f16(a1, b, acc[1][nt], 0, 0, 0);
        }
    }

    // ---- attn scalars from fp32 acc ----
    float psum[2][4][2], pdum[2][4][2];  // [mt][reg][head]
#pragma unroll
    for (int mt = 0; mt < 2; ++mt)
#pragma unroll
        for (int r = 0; r < 4; ++r) {
            psum[mt][r][0] = psum[mt][r][1] = 0.f;
            pdum[mt][r][0] = pdum[mt][r][1] = 0.f;
        }
#pragma unroll
    for (int nt = 0; nt < NT; ++nt) {
        float av = atts[nt * 16 + lm];
        float dv = attd[nt * 16 + lm];
        int hh = nt / HT;
#pragma unroll
        for (int mt = 0; mt < 2; ++mt)
#pragma unroll
            for (int r = 0; r < 4; ++r) {
                psum[mt][r][hh] = fmaf(acc[mt][nt][r], av, psum[mt][r][hh]);
                pdum[mt][r][hh] = fmaf(acc[mt][nt][r], dv, pdum[mt][r][hh]);
            }
    }
#pragma unroll
    for (int o = 1; o < 16; o <<= 1) {
#pragma unroll
        for (int mt = 0; mt < 2; ++mt)
#pragma unroll
            for (int r = 0; r < 4; ++r) {
                psum[mt][r][0] += __shfl_xor(psum[mt][r][0], o);
                psum[mt][r][1] += __shfl_xor(psum[mt][r][1], o);
                pdum[mt][r][0] += __shfl_xor(pdum[mt][r][0], o);
                pdum[mt][r][1] += __shfl_xor(pdum[mt][r][1], o);
            }
    }
    if (lm == 0) {
#pragma unroll
        for (int mt = 0; mt < 2; ++mt)
#pragma unroll
            for (int r = 0; r < 4; ++r) {
                int gr = row0 + wv * 32 + mt * 16 + quad * 4 + r;
                if (gr < N) {
                    *(float2*)&a_s[gr * 2] = make_float2(psum[mt][r][0], psum[mt][r][1]);
                    *(float2*)&a_d[gr * 2] = make_float2(pdum[mt][r][0], pdum[mt][r][1]);
                }
            }
    }

    // ---- h -> fp16 via LDS transpose (reuse sA), coalesced store ----
    __syncthreads();
    _Float16* sH = sA;  // BM*FOUT <= BM*FIN
#pragma unroll
    for (int mt = 0; mt < 2; ++mt)
#pragma unroll
        for (int nt = 0; nt < NT; ++nt)
#pragma unroll
            for (int r = 0; r < 4; ++r)
                sH[(wv * 32 + mt * 16 + quad * 4 + r) * FOUT + nt * 16 + lm] =
                    (_Float16)acc[mt][nt][r];
    __syncthreads();
    for (int idx = tid; idx < BM * FOUT / 8; idx += 256) {
        int r = idx / (FOUT / 8), c8 = idx % (FOUT / 8);
        int gr = row0 + r;
        if (gr < N)
            *(int4*)&Hh[(size_t)gr * FOUT + c8 * 8] = *(const int4*)&sH[r * FOUT + c8 * 8];
    }
}

// --------------------- fused weighted gather aggregation ------------------
// One wave per node, no LDS. Per 64-edge chunk: lane j loads csr[j] -> src.
// Gather ADDRESSES are broadcast to lanes via __shfl of src*RI immediately
// (only dependence: the csr load), so the 4-deep h-row loads issue while the
// weight chain (a_s[src] random load -> exp) is still in flight. Weights
// reach the FMA via 2 __shfl + select. LPE lanes per edge (C=64: LPE=16,
// NG=4; C=32: LPE=8, NG=8); lane loads int4 = 8 channels; fma_mix.
// Remainder: C=64 keeps R15's 1-deep serial remainder (32-VGPR floor);
// C=32 uses the grouped remainder (deg<=24 rows: 3 serial L3 round-trips
// -> 1). Pad slots: e=0, src=0 -> fma no-op. Normalization deferred:
// av *= 0.5/denom[head] before the head fold.

__device__ __forceinline__ float lrelu02(float x) { return x > 0.f ? x : 0.2f * x; }

template <int C, bool ELU, typename OT>
__launch_bounds__(256)
__global__ void aggregate_kernel(const __half* __restrict__ Hh,
                                 const float* __restrict__ a_s, const float* __restrict__ a_d,
                                 const int* __restrict__ rowptr, const int* __restrict__ csr,
                                 const float* __restrict__ bias, OT* __restrict__ out, int N) {
    constexpr int LPE = (C == 64) ? 16 : 8;   // lanes per edge
    constexpr int NG = 64 / LPE;              // edges per batch
    constexpr int RI = C / 4;                 // int4 per h row (2C halves)
    const int wid = threadIdx.x >> 6;
    const int lane = threadIdx.x & 63;
    const int sub = lane & (LPE - 1);
    const int qid = lane / LPE;               // edge-within-batch
    const int myH = (sub >= LPE / 2);         // this lane's head
    int n = blockIdx.x * 4 + wid;
    if (n >= N) return;
    int start = rowptr[n], end = rowptr[n + 1];
    const int4* HI = (const int4*)Hh;
    float2 adn = ((const float2*)a_d)[n];

    float av[8];
#pragma unroll
    for (int j = 0; j < 8; ++j) av[j] = 0.f;
    float d0 = 0.f, d1 = 0.f;

    for (int cs = start; cs < end; cs += 64) {
        int j = cs + lane;
        int s = 0;
        if (j < end) s = csr[j];              // masked lanes: src 0
        int sri = (int)((unsigned)s * RI);
        int cnt = min(64, end - cs);
        int nbatch = (cnt + NG - 1) / NG;     // wave-uniform

        // weight chain (independent of gather addressing; overlaps h-loads)
        float2 asv = ((const float2*)a_s)[s]; // s=0 for masked lanes: safe
        float e0 = 0.f, e1 = 0.f;
        if (j < end) {
            e0 = __expf(lrelu02(asv.x + adn.x));
            e1 = __expf(lrelu02(asv.y + adn.y));
        }
        d0 += e0;
        d1 += e1;

        int b = 0;
        for (; b + 4 <= nbatch; b += 4) {     // 4-deep exact main
            int adr[4];
#pragma unroll
            for (int u = 0; u < 4; ++u)
                adr[u] = __shfl(sri, (b + u) * NG + qid);   // addr: csr-only dep
            int4 hv[4];
#pragma unroll
            for (int u = 0; u < 4; ++u)
                hv[u] = HI[(unsigned)adr[u] + (unsigned)sub];
#pragma unroll
            for (int u = 0; u < 4; ++u) {
                int slot = (b + u) * NG + qid;
                float w0 = __shfl(e0, slot);
                float w1 = __shfl(e1, slot);
                float ww = myH ? w1 : w0;
                const _Float16* hh = (const _Float16*)&hv[u];
#pragma unroll
                for (int k = 0; k < 8; ++k)
                    av[k] = fmaf(ww, (float)hh[k], av[k]);  // v_fma_mix_f32
            }
        }
        if constexpr (C == 32) {
            int rem = nbatch - b;             // 0..3, wave-uniform
            if (rem > 0) {                    // grouped remainder (agg2 only)
                int4 hvr[3];
#pragma unroll
                for (int u = 0; u < 3; ++u) {
                    if (u < rem) {            // wave-uniform guard
                        int adr = __shfl(sri, (b + u) * NG + qid);
                        hvr[u] = HI[(unsigned)adr + (unsigned)sub];
                    }
                }
#pragma unroll
                for (int u = 0; u < 3; ++u) {
                    if (u < rem) {            // wave-uniform guard
                        int slot = (b + u) * NG + qid;
                        float w0 = __shfl(e0, slot);
                        float w1 = __shfl(e1, slot);
                        float ww = myH ? w1 : w0;
                        const _Float16* hh = (const _Float16*)&hvr[u];
#pragma unroll
                        for (int k = 0; k < 8; ++k)
                            av[k] = fmaf(ww, (float)hh[k], av[k]);
                    }
                }
            }
        } else {
            for (; b < nbatch; ++b) {         // 1-deep serial remainder (agg1)
                int slot = b * NG + qid;
                int adr = __shfl(sri, slot);
                int4 hv = HI[(unsigned)adr + (unsigned)sub];
                float w0 = __shfl(e0, slot);
                float w1 = __shfl(e1, slot);
                float ww = myH ? w1 : w0;
                const _Float16* hh = (const _Float16*)&hv;
#pragma unroll
                for (int k = 0; k < 8; ++k)
                    av[k] = fmaf(ww, (float)hh[k], av[k]);  // v_fma_mix_f32
            }
        }
    }

    // merge edge subsets (groups of LPE lanes)
#pragma unroll
    for (int o = LPE; o < 64; o <<= 1)
#pragma unroll
        for (int j = 0; j < 8; ++j) av[j] += __shfl_xor(av[j], o);
    // denominator: every lane holds a partial (one edge-slot per chunk)
#pragma unroll
    for (int o = 32; o > 0; o >>= 1) {
        d0 += __shfl_xor(d0, o);
        d1 += __shfl_xor(d1, o);
    }
    float sc = myH ? (0.5f / d1) : (0.5f / d0);  // 0.5 = head mean
#pragma unroll
    for (int j = 0; j < 8; ++j) av[j] *= sc;
    // head fold: ch c (head0) + ch c+C (head1)
#pragma unroll
    for (int j = 0; j < 8; ++j) av[j] += __shfl_xor(av[j], LPE / 2);

    if (lane < LPE / 2) {
        float4 b0 = *(const float4*)(bias + sub * 8);
        float4 b1 = *(const float4*)(bias + sub * 8 + 4);
        float o0[8];
        o0[0] = av[0] + b0.x; o0[1] = av[1] + b0.y;
        o0[2] = av[2] + b0.z; o0[3] = av[3] + b0.w;
        o0[4] = av[4] + b1.x; o0[5] = av[5] + b1.y;
        o0[6] = av[6] + b1.z; o0[7] = av[7] + b1.w;
        if (ELU) {
#pragma unroll
            for (int j = 0; j < 8; ++j) o0[j] = o0[j] > 0.f ? o0[j] : expm1f(o0[j]);
        }
        if (sizeof(OT) == 2) {
            union { int4 v; __half2 h2[4]; } u;
#pragma unroll
            for (int p = 0; p < 4; ++p) u.h2[p] = __floats2half2_rn(o0[2 * p], o0[2 * p + 1]);
            *(int4*)((__half*)out + (size_t)n * C + sub * 8) = u.v;
        } else {
            *(float4*)((float*)out + (size_t)n * C + sub * 8) =
                make_float4(o0[0], o0[1], o0[2], o0[3]);
            *(float4*)((float*)out + (size_t)n * C + sub * 8 + 4) =
                make_float4(o0[4], o0[5], o0[6], o0[7]);
        }
    }
}

// ------------------------- launch -------------------------

extern "C" void kernel_launch(void* const* d_in, const int* in_sizes, int n_in,
                              void* d_out, int out_size, void* d_ws, size_t ws_size,
                              hipStream_t stream) {
    const float* x    = (const float*)d_in[0];
    const int*   eidx = (const int*)d_in[1];
    const float* W1   = (const float*)d_in[2];
    const float* as1w = (const float*)d_in[3];
    const float* ad1w = (const float*)d_in[4];
    const float* b1   = (const float*)d_in[5];
    const float* W2   = (const float*)d_in[6];
    const float* as2w = (const float*)d_in[7];
    const float* ad2w = (const float*)d_in[8];
    const float* b2   = (const float*)d_in[9];
    float* out = (float*)d_out;

    const int N = in_sizes[0] / 128;  // Fin = 128
    const int E = in_sizes[1] / 2;
    const int NBK = (N + (1 << BINBITS) - 1) >> BINBITS;

    char* base = (char*)d_ws;
    size_t off = 0;
    auto alloc = [&](size_t bytes) {
        size_t cur = off;
        off += (bytes + 255) & ~(size_t)255;
        return (void*)(base + cur);
    };

    int* rowptr   = (int*)alloc((size_t)(N + 1) * 4);
    int* csr      = (int*)alloc((size_t)(E + N) * 4);
    int* bcbf     = (int*)alloc((size_t)512 * 4);        // [0:256)=bcnt, [256:512)=bfill
    unsigned* binned = (unsigned*)alloc((size_t)E * 4);
    __half* h1    = (__half*)alloc((size_t)N * 128 * 2);  // fp16, reused as h2
    __half* x2h   = (__half*)alloc((size_t)N * 64 * 2);   // fp16 layer-2 input
    float* a_s    = (float*)alloc((size_t)N * 2 * 4);
    float* a_d    = (float*)alloc((size_t)N * 2 * 4);
    _Float16* Wt1 = (_Float16*)alloc((size_t)128 * 128 * 2);
    _Float16* Wt2 = (_Float16*)alloc((size_t)64 * 64 * 2);

    int* bcnt  = bcbf;
    int* bfill = bcbf + 256;
    const int* esrc = eidx;
    const int* edst = eidx + E;

    // --- init + weight conversion (coalesced) ---
    hipMemsetAsync(bcbf, 0, 512 * 4, stream);
    wcvt_kernel<<<(128 * 128 + 64 * 64 + 255) / 256, 256, 0, stream>>>(W1, Wt1, W2, Wt2);

    // --- Layer 1 GEMM fused with bucket-hist (independent roots) ---
    const int gemm1Blocks = (N + 127) / 128;
    gemm_attn_mfma<128, 128, float>
        <<<256 + gemm1Blocks, 256, 0, stream>>>(x, Wt1, as1w, ad1w, h1, a_s, a_d, N,
                                                edst, bcnt, E, 256);

    // --- CSR build (shared by both layers) ---
    binA_kernel<<<(E + CHUNK - 1) / CHUNK, 256, 0, stream>>>(esrc, edst, bcnt, bfill, binned, E);
    binB_kernel<<<NBK, 512, 0, stream>>>(binned, bcnt, rowptr, csr, N);

    // --- Layer 1 aggregate ---
    aggregate_kernel<64, true, __half>
        <<<(N + 3) / 4, 256, 0, stream>>>(h1, a_s, a_d, rowptr, csr, b1, x2h, N);

    // --- Layer 2 (Fin=64 -> H=2, C=32) ---
    gemm_attn_mfma<64, 64, __half>
        <<<(N + 127) / 128, 256, 0, stream>>>(x2h, Wt2, as2w, ad2w, h1, a_s, a_d, N,
                                              nullptr, nullptr, 0, 0);
    aggregate_kernel<32, false, float>
        <<<(N + 3) / 4, 256, 0, stream>>>(h1, a_s, a_d, rowptr, csr, b2, out, N);
}